// Round 12
// baseline (121.089 us; speedup 1.0000x reference)
//
#include <hip/hip_runtime.h>
#include <stdint.h>

typedef unsigned short u16;
typedef signed char i8t;
typedef __attribute__((ext_vector_type(4))) int i32x4;

#define NIMG 32
#define CH   512         // Cin == Cout == 512
#define HP   30          // padded
#define WP   30
#define PIX  784         // 28*28
#define KSZ  4608        // 512*9
#define ALPHA_C 0.2f
#define NKT  36          // K tiles of 128 (i8)
#define BM   128

// ---- async global->LDS, 16B per lane (LDS dest = wave-uniform base + lane*16) ----
__device__ __forceinline__ void gload16(const void* g, void* l) {
  __builtin_amdgcn_global_load_lds((const __attribute__((address_space(1))) void*)g,
                                   (__attribute__((address_space(3))) void*)l, 16, 0, 0);
}

// ---- block (256-thread) sum reduction ----
__device__ __forceinline__ float blocksum256(float v, float* red) {
  v += __shfl_down(v, 32); v += __shfl_down(v, 16); v += __shfl_down(v, 8);
  v += __shfl_down(v, 4);  v += __shfl_down(v, 2);  v += __shfl_down(v, 1);
  const int t = threadIdx.x;
  __syncthreads();
  if ((t & 63) == 0) red[t >> 6] = v;
  __syncthreads();
  return red[0] + red[1] + red[2] + red[3];
}

// ================= weight transform -> int8 {-1,0,+1}, FRAGMENT-ORDERED =================
// Wt2 layout: frag (ob=o/16, kt, ks) is 1024B: [kq*16+rl]*16 + byte  (rl=o%16).
__global__ __launch_bounds__(256) void wker(const float* __restrict__ w,
                                            const float* __restrict__ gain,
                                            i8t* __restrict__ Wt2,
                                            float* __restrict__ wsc) {
  __shared__ float sw[KSZ];
  __shared__ float red[4];
  const int o = blockIdx.x;
  const int t = threadIdx.x;
  const float* wo = w + (size_t)o * KSZ;

  float s = 0.f;
  for (int j = t; j < KSZ; j += 256) { float v = wo[j]; sw[j] = v; s += v; }
  const float mean = blocksum256(s, red) * (1.f / 4608.f);

  float s2 = 0.f;
  for (int j = t; j < KSZ; j += 256) { float d = sw[j] - mean; s2 += d * d; }
  const float var  = blocksum256(s2, red) * (1.f / 4608.f);
  const float stdv = sqrtf(var);
  const float scale = 1.0f / sqrtf(4608.0f);
  const float inv = scale / (stdv + 1e-5f);

  const int ob = o >> 4, rl = o & 15;
  float sa = 0.f;
  for (int j = t; j < KSZ; j += 256) {
    float ws = (sw[j] - mean) * inv;
    sa += fabsf(ws);
    i8t u = ws > 0.f ? (i8t)1 : (ws < 0.f ? (i8t)-1 : (i8t)0);
    int k = (j % 9) * 512 + (j / 9);               // K order: (kh*3+kw)*512 + ci
    int kt = k >> 7, ks = (k >> 6) & 1, kq = (k >> 4) & 3, kb = k & 15;
    Wt2[(((size_t)ob * 72 + kt * 2 + ks) * 64 + kq * 16 + rl) * 16 + kb] = u;
  }
  const float sf = blocksum256(sa, red) * (1.f / 4608.f);
  if (t == 0) wsc[o] = sf * gain[o] * ALPHA_C;
}

// ================= input binarize + NCHW -> padded NHWC int8 (+halo zero) =================
__global__ __launch_bounds__(256) void bker(const float* __restrict__ x,
                                            const float* __restrict__ mb0,
                                            i8t* __restrict__ P) {
  __shared__ float tile[64][57];
  const int pc = blockIdx.x;             // 14 pixel chunks of 56
  const int cc = blockIdx.y;             // 8 ci chunks of 64
  const int n  = blockIdx.z;
  const int p0 = pc * 56;
  const int ci0 = cc * 64;
  const int t = threadIdx.x;

  if (pc == 0) {                          // halo zeroing
    for (int i = t; i < 116 * 16; i += 256) {
      int pos = i >> 4, wq = i & 15;
      int hp, wp;
      if (pos < 30)      { hp = 0;        wp = pos; }
      else if (pos < 60) { hp = 29;       wp = pos - 30; }
      else if (pos < 88) { hp = pos - 59; wp = 0; }
      else               { hp = pos - 87; wp = 29; }
      uint32_t* dst = (uint32_t*)(P + (((size_t)n * HP + hp) * WP + wp) * CH + ci0);
      dst[wq] = 0u;
    }
  }

  const float* xb = x + ((size_t)n * CH + ci0) * PIX + p0;
  for (int i = t; i < 64 * 56; i += 256) {
    int ci = i / 56, p = i - ci * 56;
    tile[ci][p] = xb[(size_t)ci * PIX + p];
  }
  __syncthreads();
  for (int i = t; i < 56 * 16; i += 256) {
    int p = i >> 4, c4 = (i & 15) << 2;
    uint32_t pk = 0;
#pragma unroll
    for (int j = 0; j < 4; ++j) {
      float v = tile[c4 + j][p] + mb0[ci0 + c4 + j];       // BETA = 1.0
      uint32_t u = v > 0.f ? 1u : (v < 0.f ? 0xffu : 0u);
      pk |= u << (8 * j);
    }
    int pg = p0 + p;
    int h = pg / 28, wq = pg - h * 28;
    *(uint32_t*)(P + (((size_t)n * HP + (h + 1)) * WP + (wq + 1)) * CH + ci0 + c4) = pk;
  }
}

// ================= binary implicit-GEMM conv (i8 MFMA) + fused epilogue =================
// 128x128 tile, BK=128, 4 waves as 2x2 (wave = 64x64): A-dup 2x (not 4x) ->
// LDS-read chip-floor 17.6us vs MFMA 30us -> MFMA is the single top pipe.
// grid 784 -> 3 blocks/CU. A: triple-buffered LDS 48KB staged 2 ahead;
// B: direct global->VGPR ping-pong 1 tile ahead. 1 barrier/tile, vmcnt(4).
__global__ __launch_bounds__(256, 3) void gemm_bin(const i8t* __restrict__ P,
                                                   const i8t* __restrict__ Wt2,
                                                   const float* __restrict__ wsc,
                                                   const float* __restrict__ x,
                                                   const float* __restrict__ mb1,
                                                   const float* __restrict__ pa,
                                                   const float* __restrict__ mb2,
                                                   float* __restrict__ out) {
  __shared__ i8t As[3][BM * 128];    // 16 KB each

  // bijective XCD swizzle: 784 = 98*8
  const int bid = blockIdx.x;
  const int swz = (bid & 7) * 98 + (bid >> 3);
  const int bm = swz >> 2, bn = swz & 3;
  const int m0 = bm * BM, o0 = bn * 128;

  const int t = threadIdx.x;
  const int lane = t & 63, wid = t >> 6;
  const int wr = wid >> 1, wc = wid & 1;            // 2x2 wave grid; wave = 64x64

  // ---- A staging: 8 chunks of 16B per 128B row; 32 rows/round, 4 rounds ----
  const int c8 = t & 7;
  const int rbase = t >> 3;                         // 0..31; dest row = it*32+rbase
  const int swko = (c8 * 16) ^ ((rbase & 7) << 4);  // pre-swizzled src byte offset

  size_t apix[4];
#pragma unroll
  for (int it = 0; it < 4; ++it) {
    int m = m0 + it * 32 + rbase;
    int n = m / PIX;
    int pix = m - n * PIX;
    int h = pix / 28, wq = pix - h * 28;
    apix[it] = (((size_t)n * HP + h) * WP + wq) * CH + swko;
  }
  const int obi = (o0 >> 4) + wc * 4;               // 4 B frag-cols per wave

  i32x4 acc[4][4] = {};

  auto stage = [&](int s, int kt) {                 // A: 4 gloads/thread (16 KB)
    const int pos = kt >> 2;                        // kh*3+kw
    const int kh = pos / 3, kw = pos - kh * 3;
    const size_t aoff = (size_t)(kh * WP + kw) * CH + (size_t)(kt & 3) * 128;
#pragma unroll
    for (int it = 0; it < 4; ++it)
      gload16(P + apix[it] + aoff, (char*)&As[s][0] + it * 4096 + wid * 1024);
  };

  auto loadB = [&](i32x4* v0, i32x4* v1, int kt) {  // 8 coalesced 1KB/wave loads
#pragma unroll
    for (int nf = 0; nf < 4; ++nf) {
      const size_t fo = ((size_t)(obi + nf) * 72 + (size_t)kt * 2) * 1024 + lane * 16;
      v0[nf] = *(const i32x4*)(Wt2 + fo);
      v1[nf] = *(const i32x4*)(Wt2 + fo + 1024);
    }
  };

  const int kq = lane >> 4, rl = lane & 15;

  auto computeT = [&](int s, const i32x4* b0, const i32x4* b1) {
#pragma unroll
    for (int ks = 0; ks < 2; ++ks) {
      i32x4 a[4];
      const int kb = ks * 64 + kq * 16;
#pragma unroll
      for (int mf = 0; mf < 4; ++mf) {
        int r = wr * 64 + mf * 16 + rl;
        a[mf] = *(const i32x4*)(&As[s][r * 128 + (kb ^ ((r & 7) << 4))]);
      }
      __builtin_amdgcn_s_setprio(1);
#pragma unroll
      for (int mf = 0; mf < 4; ++mf)
#pragma unroll
        for (int nf = 0; nf < 4; ++nf)
          acc[mf][nf] = __builtin_amdgcn_mfma_i32_16x16x64_i8(
              a[mf], ks ? b1[nf] : b0[nf], acc[mf][nf], 0, 0, 0);
      __builtin_amdgcn_s_setprio(0);
    }
  };

#define WB4 asm volatile("s_waitcnt vmcnt(4)\n\ts_barrier" ::: "memory")
#define WB0 asm volatile("s_waitcnt vmcnt(0)\n\ts_barrier" ::: "memory")

  i32x4 bX0[4], bX1[4], bY0[4], bY1[4];

  // prologue: A(0)->buf0 [4], B(0)->bX [8], A(1)->buf1 [4]
  stage(0, 0);
  loadB(bX0, bX1, 0);
  stage(1, 1);

  // steady-state at tile-top: outstanding [A(kt):4, B(kt):8, A(kt+1):4];
  // vmcnt(4) drains A(kt)+B(kt), keeps A(kt+1) in flight.
  int kt = 0;
  for (; kt + 2 < NKT; kt += 2) {
    WB4;
    loadB(bY0, bY1, kt + 1);
    stage((kt + 2) % 3, kt + 2);
    computeT(kt % 3, bX0, bX1);
    WB4;
    loadB(bX0, bX1, kt + 2);
    stage((kt + 3) % 3, kt + 3);           // kt+3 <= NKT-1 here
    computeT((kt + 1) % 3, bY0, bY1);
  }
  // kt == NKT-2: outstanding [A(34):4, B(34):8, A(35):4]
  WB4;
  loadB(bY0, bY1, NKT - 1);
  computeT((NKT - 2) % 3, bX0, bX1);
  WB0;
  computeT((NKT - 1) % 3, bY0, bY1);

#undef WB4
#undef WB0

  // ---- fused epilogue: *wsc + residual + b1 -> PReLU -> + b2 ----
  const int ccol = lane & 15;
  const int rq4 = (lane >> 4) * 4;
#pragma unroll
  for (int nf = 0; nf < 4; ++nf) {
    const int o = o0 + wc * 64 + nf * 16 + ccol;
    const float wv = wsc[o];
    const float b1 = mb1[o];
    const float ap = pa[o];
    const float b2 = mb2[o];
#pragma unroll
    for (int mf = 0; mf < 4; ++mf) {
      const int m = m0 + wr * 64 + mf * 16 + rq4;
      const int n = m / PIX;
      const int pix = m - n * PIX;
      const size_t base = ((size_t)(n * CH + o)) * PIX + pix;  // NCHW fp32
      const float4 r = *reinterpret_cast<const float4*>(x + base);
      const float rv[4] = {r.x, r.y, r.z, r.w};
      float4 ov;
      float* po = &ov.x;
#pragma unroll
      for (int q = 0; q < 4; ++q) {
        float v = (float)acc[mf][nf][q] * wv + rv[q] + b1;
        v = v >= 0.f ? v : ap * v;
        po[q] = v + b2;
      }
      *reinterpret_cast<float4*>(out + base) = ov;
    }
  }
}

extern "C" void kernel_launch(void* const* d_in, const int* in_sizes, int n_in,
                              void* d_out, int out_size, void* d_ws, size_t ws_size,
                              hipStream_t stream) {
  const float* x    = (const float*)d_in[0];
  const float* mb0  = (const float*)d_in[1];
  const float* w    = (const float*)d_in[2];
  const float* gain = (const float*)d_in[3];
  const float* mb1  = (const float*)d_in[4];
  const float* pa   = (const float*)d_in[5];
  const float* mb2  = (const float*)d_in[6];
  float* out = (float*)d_out;

  char* ws = (char*)d_ws;
  const size_t P_BYTES  = (size_t)NIMG * HP * WP * CH;   // 14,745,600 (i8)
  const size_t WT_BYTES = (size_t)CH * KSZ;              //  2,359,296 (i8)
  i8t*   P   = (i8t*)ws;
  i8t*   Wt2 = (i8t*)(ws + P_BYTES);
  float* wv  = (float*)(ws + P_BYTES + WT_BYTES);

  wker<<<512, 256, 0, stream>>>(w, gain, Wt2, wv);
  bker<<<dim3(14, 8, NIMG), 256, 0, stream>>>(x, mb0, P);   // also zeroes halo
  gemm_bin<<<784, 256, 0, stream>>>(P, Wt2, wv, x, mb1, pa, mb2, out);
}

// Round 13
// 92.533 us; speedup vs baseline: 1.3086x; 1.3086x over previous
//
#include <hip/hip_runtime.h>
#include <stdint.h>

typedef unsigned short u16;
typedef signed char i8t;
typedef __attribute__((ext_vector_type(4))) int i32x4;

#define NIMG 32
#define CH   512         // Cin == Cout == 512
#define HP   30          // padded
#define WP   30
#define PIX  784         // 28*28
#define KSZ  4608        // 512*9
#define ALPHA_C 0.2f
#define NKT  36          // K tiles of 128 (i8)
#define BM   112

// ---- async global->LDS, 16B per lane (LDS dest = wave-uniform base + lane*16) ----
__device__ __forceinline__ void gload16(const void* g, void* l) {
  __builtin_amdgcn_global_load_lds((const __attribute__((address_space(1))) void*)g,
                                   (__attribute__((address_space(3))) void*)l, 16, 0, 0);
}

// ---- block (256-thread) sum reduction ----
__device__ __forceinline__ float blocksum256(float v, float* red) {
  v += __shfl_down(v, 32); v += __shfl_down(v, 16); v += __shfl_down(v, 8);
  v += __shfl_down(v, 4);  v += __shfl_down(v, 2);  v += __shfl_down(v, 1);
  const int t = threadIdx.x;
  __syncthreads();
  if ((t & 63) == 0) red[t >> 6] = v;
  __syncthreads();
  return red[0] + red[1] + red[2] + red[3];
}

// ================= merged prep: input binarize (blocks 0..3583) + weight
// transform (blocks 3584..4095). Both memory-bound, co-scheduled in one
// dispatch to overlap and save a launch gap. =================
__global__ __launch_bounds__(256) void prep(const float* __restrict__ x,
                                            const float* __restrict__ mb0,
                                            const float* __restrict__ w,
                                            const float* __restrict__ gain,
                                            i8t* __restrict__ P,
                                            i8t* __restrict__ Wt2,
                                            float* __restrict__ wsc) {
  __shared__ float smem[4612];           // union: tile[64][57]=3648 | sw[4608]+red[4]
  const int bid = blockIdx.x;
  const int t = threadIdx.x;

  if (bid < 3584) {
    // ---------------- bker part: binarize + NCHW -> padded NHWC int8 ----------------
    float (*tile)[57] = (float(*)[57])smem;
    const int pc = bid % 14;             // 14 pixel chunks of 56
    const int cc = (bid / 14) & 7;       // 8 ci chunks of 64
    const int n  = bid / 112;            // 32 images
    const int p0 = pc * 56;
    const int ci0 = cc * 64;

    if (pc == 0) {                        // halo zeroing
      for (int i = t; i < 116 * 16; i += 256) {
        int pos = i >> 4, wq = i & 15;
        int hp, wp;
        if (pos < 30)      { hp = 0;        wp = pos; }
        else if (pos < 60) { hp = 29;       wp = pos - 30; }
        else if (pos < 88) { hp = pos - 59; wp = 0; }
        else               { hp = pos - 87; wp = 29; }
        uint32_t* dst = (uint32_t*)(P + (((size_t)n * HP + hp) * WP + wp) * CH + ci0);
        dst[wq] = 0u;
      }
    }

    const float* xb = x + ((size_t)n * CH + ci0) * PIX + p0;
    for (int i = t; i < 64 * 56; i += 256) {
      int ci = i / 56, p = i - ci * 56;
      tile[ci][p] = xb[(size_t)ci * PIX + p];
    }
    __syncthreads();
    for (int i = t; i < 56 * 16; i += 256) {
      int p = i >> 4, c4 = (i & 15) << 2;
      uint32_t pk = 0;
#pragma unroll
      for (int j = 0; j < 4; ++j) {
        float v = tile[c4 + j][p] + mb0[ci0 + c4 + j];     // BETA = 1.0
        uint32_t u = v > 0.f ? 1u : (v < 0.f ? 0xffu : 0u);
        pk |= u << (8 * j);
      }
      int pg = p0 + p;
      int h = pg / 28, wq = pg - h * 28;
      *(uint32_t*)(P + (((size_t)n * HP + (h + 1)) * WP + (wq + 1)) * CH + ci0 + c4) = pk;
    }
  } else {
    // ---------------- wker part: weight standardize -> int8, fragment-ordered ----------------
    // Wt2 layout: frag (ob=o/16, kt, ks) is 1024B: [kq*16+rl]*16 + byte (rl=o%16).
    float* sw  = smem;
    float* red = smem + 4608;
    const int o = bid - 3584;
    const float* wo = w + (size_t)o * KSZ;

    float s = 0.f;
    for (int j = t; j < KSZ; j += 256) { float v = wo[j]; sw[j] = v; s += v; }
    const float mean = blocksum256(s, red) * (1.f / 4608.f);

    float s2 = 0.f;
    for (int j = t; j < KSZ; j += 256) { float d = sw[j] - mean; s2 += d * d; }
    const float var  = blocksum256(s2, red) * (1.f / 4608.f);
    const float stdv = sqrtf(var);
    const float scale = 1.0f / sqrtf(4608.0f);
    const float inv = scale / (stdv + 1e-5f);

    const int ob = o >> 4, rl = o & 15;
    float sa = 0.f;
    for (int j = t; j < KSZ; j += 256) {
      float ws = (sw[j] - mean) * inv;
      sa += fabsf(ws);
      i8t u = ws > 0.f ? (i8t)1 : (ws < 0.f ? (i8t)-1 : (i8t)0);
      int k = (j % 9) * 512 + (j / 9);             // K order: (kh*3+kw)*512 + ci
      int kt = k >> 7, ks = (k >> 6) & 1, kq = (k >> 4) & 3, kb = k & 15;
      Wt2[(((size_t)ob * 72 + kt * 2 + ks) * 64 + kq * 16 + rl) * 16 + kb] = u;
    }
    const float sf = blocksum256(sa, red) * (1.f / 4608.f);
    if (t == 0) wsc[o] = sf * gain[o] * ALPHA_C;
  }
}

// ================= binary implicit-GEMM conv (i8 MFMA) + fused epilogue =================
// == round-9 verbatim (best measured: 70.2us) ==
// 112x256 tile, BK=128, 4 waves (1x4), grid 448 -> TWO blocks/CU with
// independent barrier domains (desync overlap). A: triple-buffered LDS 48KB,
// staged 2 ahead; B: direct global->VGPR, register ping-pong 1 tile ahead.
// 1 barrier/tile, counted vmcnt.
__global__ __launch_bounds__(256, 2) void gemm_bin(const i8t* __restrict__ P,
                                                   const i8t* __restrict__ Wt2,
                                                   const float* __restrict__ wsc,
                                                   const float* __restrict__ x,
                                                   const float* __restrict__ mb1,
                                                   const float* __restrict__ pa,
                                                   const float* __restrict__ mb2,
                                                   float* __restrict__ out) {
  __shared__ i8t As[3][128 * 128];   // 16 KB each (rows 112..127 = clamp slack)

  // bijective XCD swizzle: 448 = 56*8
  const int bid = blockIdx.x;
  const int swz = (bid & 7) * 56 + (bid >> 3);
  const int bm = swz >> 1, bn = swz & 1;
  const int m0 = bm * BM, o0 = bn * 256;

  const int t = threadIdx.x;
  const int lane = t & 63, wid = t >> 6;
  const int wc = wid;                               // 1x4 wave grid; wave = 112x64

  // ---- A staging: 8 chunks of 16B per 128B row; 32 rows/round, 4 rounds ----
  const int c8 = t & 7;
  const int rbase = t >> 3;                         // 0..31; dest row = it*32+rbase
  const int swko = (c8 * 16) ^ ((rbase & 7) << 4);  // pre-swizzled src byte offset

  size_t apix[4];
#pragma unroll
  for (int it = 0; it < 4; ++it) {
    int m = m0 + it * 32 + rbase;
    if (m > m0 + BM - 1) m = m0 + BM - 1;           // clamp (uniform instr count)
    int n = m / PIX;
    int pix = m - n * PIX;
    int h = pix / 28, wq = pix - h * 28;
    apix[it] = (((size_t)n * HP + h) * WP + wq) * CH + swko;
  }
  const int obi = (o0 >> 4) + wc * 4;               // B frag-block base for this wave

  i32x4 acc[7][4] = {};

  auto stage = [&](int s, int kt) {                 // A: 4 gloads/thread (16 KB)
    const int pos = kt >> 2;                        // kh*3+kw
    const int kh = pos / 3, kw = pos - kh * 3;
    const size_t aoff = (size_t)(kh * WP + kw) * CH + (size_t)(kt & 3) * 128;
#pragma unroll
    for (int it = 0; it < 4; ++it)
      gload16(P + apix[it] + aoff, (char*)&As[s][0] + it * 4096 + wid * 1024);
  };

  auto loadB = [&](i32x4* v0, i32x4* v1, int kt) {  // 8 coalesced 1KB/wave loads
#pragma unroll
    for (int nf = 0; nf < 4; ++nf) {
      const size_t fo = ((size_t)(obi + nf) * 72 + (size_t)kt * 2) * 1024 + lane * 16;
      v0[nf] = *(const i32x4*)(Wt2 + fo);
      v1[nf] = *(const i32x4*)(Wt2 + fo + 1024);
    }
  };

  const int kq = lane >> 4, rl = lane & 15;

  auto computeT = [&](int s, const i32x4* b0, const i32x4* b1) {
#pragma unroll
    for (int ks = 0; ks < 2; ++ks) {
      i32x4 a[7];
      const int kb = ks * 64 + kq * 16;
#pragma unroll
      for (int mf = 0; mf < 7; ++mf) {
        int r = mf * 16 + rl;
        a[mf] = *(const i32x4*)(&As[s][r * 128 + (kb ^ ((r & 7) << 4))]);
      }
      __builtin_amdgcn_s_setprio(1);
#pragma unroll
      for (int mf = 0; mf < 7; ++mf)
#pragma unroll
        for (int nf = 0; nf < 4; ++nf)
          acc[mf][nf] = __builtin_amdgcn_mfma_i32_16x16x64_i8(
              a[mf], ks ? b1[nf] : b0[nf], acc[mf][nf], 0, 0, 0);
      __builtin_amdgcn_s_setprio(0);
    }
  };

#define WB2 asm volatile("s_waitcnt vmcnt(2)\n\ts_barrier" ::: "memory")
#define WB0 asm volatile("s_waitcnt vmcnt(0)\n\ts_barrier" ::: "memory")

  i32x4 bX0[4], bX1[4], bY0[4], bY1[4];

  // prologue: A(0)->buf0, B(0)->bX, A(1)->buf1
  stage(0, 0);
  loadB(bX0, bX1, 0);
  stage(1, 1);

  int kt = 0;
  for (; kt + 2 < NKT; kt += 2) {
    WB2;                                   // A(kt),B(kt) landed
    loadB(bY0, bY1, kt + 1);
    stage((kt + 2) % 3, kt + 2);
    computeT(kt % 3, bX0, bX1);
    WB2;                                   // A(kt+1),B(kt+1) landed
    loadB(bX0, bX1, kt + 2);
    stage((kt + 3) % 3, kt + 3);           // kt+3 <= NKT-1 here
    computeT((kt + 1) % 3, bY0, bY1);
  }
  // kt == NKT-2
  WB2;
  loadB(bY0, bY1, NKT - 1);
  computeT((NKT - 2) % 3, bX0, bX1);
  WB0;
  computeT((NKT - 1) % 3, bY0, bY1);

#undef WB2
#undef WB0

  // ---- fused epilogue: *wsc + residual + b1 -> PReLU -> + b2 ----
  const int ccol = lane & 15;
  const int rq4 = (lane >> 4) * 4;
#pragma unroll
  for (int nf = 0; nf < 4; ++nf) {
    const int o = o0 + wc * 64 + nf * 16 + ccol;
    const float wv = wsc[o];
    const float b1 = mb1[o];
    const float ap = pa[o];
    const float b2 = mb2[o];
#pragma unroll
    for (int mf = 0; mf < 7; ++mf) {
      const int m = m0 + mf * 16 + rq4;
      const int n = m / PIX;
      const int pix = m - n * PIX;
      const size_t base = ((size_t)(n * CH + o)) * PIX + pix;  // NCHW fp32
      const float4 r = *reinterpret_cast<const float4*>(x + base);
      const float rv[4] = {r.x, r.y, r.z, r.w};
      float4 ov;
      float* po = &ov.x;
#pragma unroll
      for (int q = 0; q < 4; ++q) {
        float v = (float)acc[mf][nf][q] * wv + rv[q] + b1;
        v = v >= 0.f ? v : ap * v;
        po[q] = v + b2;
      }
      *reinterpret_cast<float4*>(out + base) = ov;
    }
  }
}

extern "C" void kernel_launch(void* const* d_in, const int* in_sizes, int n_in,
                              void* d_out, int out_size, void* d_ws, size_t ws_size,
                              hipStream_t stream) {
  const float* x    = (const float*)d_in[0];
  const float* mb0  = (const float*)d_in[1];
  const float* w    = (const float*)d_in[2];
  const float* gain = (const float*)d_in[3];
  const float* mb1  = (const float*)d_in[4];
  const float* pa   = (const float*)d_in[5];
  const float* mb2  = (const float*)d_in[6];
  float* out = (float*)d_out;

  char* ws = (char*)d_ws;
  const size_t P_BYTES  = (size_t)NIMG * HP * WP * CH;   // 14,745,600 (i8)
  const size_t WT_BYTES = (size_t)CH * KSZ;              //  2,359,296 (i8)
  i8t*   P   = (i8t*)ws;
  i8t*   Wt2 = (i8t*)(ws + P_BYTES);
  float* wv  = (float*)(ws + P_BYTES + WT_BYTES);

  prep<<<4096, 256, 0, stream>>>(x, mb0, w, gain, P, Wt2, wv);  // bker+wker merged
  gemm_bin<<<448, 256, 0, stream>>>(P, Wt2, wv, x, mb1, pa, mb2, out);
}